// Round 1
// baseline (171.340 us; speedup 1.0000x reference)
//
#include <hip/hip_runtime.h>
#include <hip/hip_bf16.h>
#include <cstdint>
#include <cstddef>

typedef __attribute__((ext_vector_type(8))) short short8;
typedef __attribute__((ext_vector_type(4))) float f32x4;
typedef unsigned short u16;
typedef unsigned int u32;

#define B_ 2
#define C_ 2048
#define D_ 1024
#define H_ 16
#define HD_ 64

static __device__ __forceinline__ u16 f2b(float f) {
  u32 x = __builtin_bit_cast(u32, f);
  x += 0x7FFFu + ((x >> 16) & 1u);
  return (u16)(x >> 16);
}

// ---------------- plain convert f32 -> bf16 ----------------
__global__ void k_convert(const float* __restrict__ in, u16* __restrict__ out, int n) {
  int i = (blockIdx.x * blockDim.x + threadIdx.x) * 4;
  const int stride = gridDim.x * blockDim.x * 4;
  for (; i < n; i += stride) {
    float4 v = *reinterpret_cast<const float4*>(in + i);
    ushort4 o;
    o.x = f2b(v.x); o.y = f2b(v.y); o.z = f2b(v.z); o.w = f2b(v.w);
    *reinterpret_cast<ushort4*>(out + i) = o;
  }
}

// ---------------- transpose + convert: in[R][Cc] f32 -> out[Cc][R] bf16 ----------------
__global__ void k_tconv(const float* __restrict__ in, u16* __restrict__ out, int R, int Cc) {
  __shared__ float tile[64][65];
  const int tC = blockIdx.x * 64;
  const int tR = blockIdx.y * 64;
  const int t = threadIdx.x;
  const int r0 = t >> 4;         // 0..15
  const int c0 = (t & 15) * 4;   // 0..60
#pragma unroll
  for (int ii = 0; ii < 4; ++ii) {
    int r = ii * 16 + r0;
    float4 v = *reinterpret_cast<const float4*>(&in[(size_t)(tR + r) * Cc + tC + c0]);
    tile[r][c0] = v.x; tile[r][c0 + 1] = v.y; tile[r][c0 + 2] = v.z; tile[r][c0 + 3] = v.w;
  }
  __syncthreads();
#pragma unroll
  for (int ii = 0; ii < 4; ++ii) {
    int c = ii * 16 + r0;  // output row (= input col)
    ushort4 o;
    o.x = f2b(tile[c0 + 0][c]);
    o.y = f2b(tile[c0 + 1][c]);
    o.z = f2b(tile[c0 + 2][c]);
    o.w = f2b(tile[c0 + 3][c]);
    *reinterpret_cast<ushort4*>(&out[(size_t)(tC + c) * R + tR + c0]) = o;
  }
}

// ---------------- async global->LDS, 16B per lane ----------------
#define GLL16(gptr, lptr) __builtin_amdgcn_global_load_lds( \
    (const __attribute__((address_space(1))) u32*)(gptr),   \
    (__attribute__((address_space(3))) u32*)(lptr), 16, 0, 0)

// ---------------- 128x128 bf16 GEMM, C = A * Bt^T + bias ----------------
// EPI 0: scatter into Q/K/V [B,H,C,hd] bf16.  EPI 1: write f32 C + bias.
template<int EPI>
__global__ __launch_bounds__(256) void k_gemm128(
    const u16* __restrict__ A, const u16* __restrict__ Bt,
    int M, int N, int K, const float* __restrict__ bias,
    u16* __restrict__ Cq, u16* __restrict__ Ck, u16* __restrict__ Cv,
    float* __restrict__ Cf)
{
  __shared__ __align__(16) u16 As[128 * 32];
  __shared__ __align__(16) u16 Bs[128 * 32];
  const int t = threadIdx.x;
  const int l = t & 63, w = t >> 6;
  const int wr = w >> 1, wc = w & 1;
  const int lr = l & 15, lg = l >> 4;
  const int m0 = blockIdx.y * 128, n0 = blockIdx.x * 128;
  f32x4 acc[4][4] = {};

  for (int k0 = 0; k0 < K; k0 += 32) {
#pragma unroll
    for (int it = 0; it < 2; ++it) {
      const int f = w * 1024 + it * 512 + l * 8;  // element index in 128x32 tile
      const int row = f >> 5, col = f & 31;
      GLL16(A + (size_t)(m0 + row) * K + k0 + col, As + w * 1024 + it * 512);
      GLL16(Bt + (size_t)(n0 + row) * K + k0 + col, Bs + w * 1024 + it * 512);
    }
    __syncthreads();
    short8 af[4], bfr[4];
#pragma unroll
    for (int m = 0; m < 4; ++m)
      af[m] = *reinterpret_cast<const short8*>(&As[(wr * 64 + m * 16 + lr) * 32 + lg * 8]);
#pragma unroll
    for (int n = 0; n < 4; ++n)
      bfr[n] = *reinterpret_cast<const short8*>(&Bs[(wc * 64 + n * 16 + lr) * 32 + lg * 8]);
#pragma unroll
    for (int m = 0; m < 4; ++m)
#pragma unroll
      for (int n = 0; n < 4; ++n)
        acc[m][n] = __builtin_amdgcn_mfma_f32_16x16x32_bf16(af[m], bfr[n], acc[m][n], 0, 0, 0);
    __syncthreads();
  }

#pragma unroll
  for (int m = 0; m < 4; ++m) {
    const int mg = m0 + wr * 64 + m * 16 + lg * 4;
#pragma unroll
    for (int n = 0; n < 4; ++n) {
      const int ng = n0 + wc * 64 + n * 16 + lr;
      const float bia = bias[ng];
      if (EPI == 0) {
        const int reg = ng >> 10, d = ng & 1023, h = d >> 6, e = d & 63;
        u16* dst = (reg == 0) ? Cq : ((reg == 1) ? Ck : Cv);
#pragma unroll
        for (int j = 0; j < 4; ++j) {
          const int mm = mg + j;
          const int b = mm >> 11, c = mm & 2047;
          dst[(((size_t)(b * H_ + h) * C_ + c) << 6) + e] = f2b(acc[m][n][j] + bia);
        }
      } else {
#pragma unroll
        for (int j = 0; j < 4; ++j)
          Cf[(size_t)(mg + j) * N + ng] = acc[m][n][j] + bia;
      }
    }
  }
}

// ---------------- V [BH][C][hd] -> Vt [BH][hd][C] ----------------
__global__ void k_vtrans(const u16* __restrict__ V, u16* __restrict__ Vt) {
  __shared__ __align__(16) u16 tl[64][72];
  const int bh = blockIdx.x >> 5;
  const int c0 = (blockIdx.x & 31) * 64;
  const int t = threadIdx.x;
#pragma unroll
  for (int ch = 0; ch < 2; ++ch) {
    const int idx = t + ch * 256;
    const int r = idx >> 3, c8 = (idx & 7) * 8;
    *reinterpret_cast<short8*>(&tl[r][c8]) =
        *reinterpret_cast<const short8*>(&V[((size_t)bh * C_ + c0 + r) * HD_ + c8]);
  }
  __syncthreads();
#pragma unroll
  for (int ch = 0; ch < 2; ++ch) {
    const int idx = t + ch * 256;
    const int d = idx >> 3, cc = (idx & 7) * 8;
    alignas(16) u16 tmp[8];
#pragma unroll
    for (int u = 0; u < 8; ++u) tmp[u] = tl[cc + u][d];
    *reinterpret_cast<short8*>(&Vt[((size_t)bh * HD_ + d) * C_ + c0 + cc]) =
        *reinterpret_cast<const short8*>(tmp);
  }
}

// ---------------- causal flash attention ----------------
// grid: 1024 blocks = (32 q-tiles reversed) x (32 bh); 256 thr = 4 waves x 16 q-rows
__global__ __launch_bounds__(256) void k_attn(
    const u16* __restrict__ Q, const u16* __restrict__ Kb, const u16* __restrict__ Vt,
    const float* __restrict__ mask, u16* __restrict__ O)
{
  __shared__ __align__(16) u16 Kl[64 * 72];
  __shared__ __align__(16) u16 Vl[64 * 72];
  __shared__ __align__(16) u16 Pl[4][16 * 72];
  const int bid = blockIdx.x;
  const int bh = bid & 31;
  const int qt = 31 - (bid >> 5);          // big tiles first (load balance heuristic)
  const int b = bh >> 4, h = bh & 15;
  const int t = threadIdx.x;
  const int l = t & 63, w = t >> 6;
  const int lr = l & 15, lg = l >> 4;
  const float scaling = 0.125f;            // hd^-0.5

  short8 aq[2];
  {
    const int qrow = qt * 64 + w * 16 + lr;
    const u16* qp = Q + ((size_t)bh * C_ + qrow) * HD_ + lg * 8;
    aq[0] = *reinterpret_cast<const short8*>(qp);
    aq[1] = *reinterpret_cast<const short8*>(qp + 32);
  }
  float mrun[4], srun[4];
  f32x4 oacc[4] = {};
#pragma unroll
  for (int j = 0; j < 4; ++j) { mrun[j] = -INFINITY; srun[j] = 0.f; }
  const int qrb = qt * 64 + w * 16 + lg * 4;
  u16* Pw = Pl[w];

  for (int kt = 0; kt <= qt; ++kt) {
    // stage K tile [64 key][64 hd] and Vt tile [64 hd][64 key], both pad-72
#pragma unroll
    for (int ch = 0; ch < 2; ++ch) {
      const int idx = t + ch * 256;
      const int r = idx >> 3, c8 = (idx & 7) * 8;
      *reinterpret_cast<short8*>(&Kl[r * 72 + c8]) =
          *reinterpret_cast<const short8*>(&Kb[((size_t)bh * C_ + kt * 64 + r) * HD_ + c8]);
      *reinterpret_cast<short8*>(&Vl[r * 72 + c8]) =
          *reinterpret_cast<const short8*>(&Vt[((size_t)bh * HD_ + r) * C_ + kt * 64 + c8]);
    }
    __syncthreads();

    // S = Q K^T  (16 q-rows x 64 keys per wave)
    f32x4 sf[4] = {};
#pragma unroll
    for (int s = 0; s < 2; ++s)
#pragma unroll
      for (int nf = 0; nf < 4; ++nf) {
        short8 bk = *reinterpret_cast<const short8*>(&Kl[(nf * 16 + lr) * 72 + s * 32 + lg * 8]);
        sf[nf] = __builtin_amdgcn_mfma_f32_16x16x32_bf16(aq[s], bk, sf[nf], 0, 0, 0);
      }

    // scale + additive mask + causal
    float p[4][4];
    float pm[4] = {-INFINITY, -INFINITY, -INFINITY, -INFINITY};
#pragma unroll
    for (int nf = 0; nf < 4; ++nf) {
      const int key = kt * 64 + nf * 16 + lr;
#pragma unroll
      for (int j = 0; j < 4; ++j) {
        const int qr = qrb + j;
        float v = sf[nf][j] * scaling + mask[((size_t)b * C_ + qr) * C_ + key];
        if (key > qr) v = -INFINITY;
        p[nf][j] = v;
        pm[j] = fmaxf(pm[j], v);
      }
    }
    // online softmax (row lives in a 16-lane group)
#pragma unroll
    for (int j = 0; j < 4; ++j) {
      pm[j] = fmaxf(pm[j], __shfl_xor(pm[j], 1));
      pm[j] = fmaxf(pm[j], __shfl_xor(pm[j], 2));
      pm[j] = fmaxf(pm[j], __shfl_xor(pm[j], 4));
      pm[j] = fmaxf(pm[j], __shfl_xor(pm[j], 8));
    }
#pragma unroll
    for (int j = 0; j < 4; ++j) {
      const float mn = fmaxf(mrun[j], pm[j]);
      const float rescale = __expf(mrun[j] - mn);   // first iter: exp(-inf)=0
      float rsum = 0.f;
#pragma unroll
      for (int nf = 0; nf < 4; ++nf) {
        const float e = __expf(p[nf][j] - mn);
        p[nf][j] = e;
        rsum += e;
      }
      rsum += __shfl_xor(rsum, 1);
      rsum += __shfl_xor(rsum, 2);
      rsum += __shfl_xor(rsum, 4);
      rsum += __shfl_xor(rsum, 8);
      srun[j] = srun[j] * rescale + rsum;
      mrun[j] = mn;
#pragma unroll
      for (int df = 0; df < 4; ++df) oacc[df][j] *= rescale;
    }

    // P -> per-wave LDS (re-fragment for PV A-operand)
#pragma unroll
    for (int nf = 0; nf < 4; ++nf)
#pragma unroll
      for (int j = 0; j < 4; ++j)
        Pw[(lg * 4 + j) * 72 + nf * 16 + lr] = f2b(p[nf][j]);
    __syncthreads();

    // O += P V  via Vt (Bt form)
#pragma unroll
    for (int s2 = 0; s2 < 2; ++s2) {
      short8 ap = *reinterpret_cast<const short8*>(&Pw[lr * 72 + s2 * 32 + lg * 8]);
#pragma unroll
      for (int df = 0; df < 4; ++df) {
        short8 bv = *reinterpret_cast<const short8*>(&Vl[(df * 16 + lr) * 72 + s2 * 32 + lg * 8]);
        oacc[df] = __builtin_amdgcn_mfma_f32_16x16x32_bf16(ap, bv, oacc[df], 0, 0, 0);
      }
    }
    __syncthreads();
  }

  // normalize + write attn_out [B,C,H,hd] bf16
#pragma unroll
  for (int df = 0; df < 4; ++df) {
    const int dcol = df * 16 + lr;
#pragma unroll
    for (int j = 0; j < 4; ++j) {
      const int qr = qrb + j;
      O[((size_t)b * C_ + qr) * D_ + h * HD_ + dcol] = f2b(oacc[df][j] / srun[j]);
    }
  }
}

extern "C" void kernel_launch(void* const* d_in, const int* in_sizes, int n_in,
                              void* d_out, int out_size, void* d_ws, size_t ws_size,
                              hipStream_t stream) {
  const float* hs   = (const float*)d_in[0];
  const float* mask = (const float*)d_in[1];
  const float* Wqkv = (const float*)d_in[2];
  const float* bqkv = (const float*)d_in[3];
  const float* Wo   = (const float*)d_in[4];
  const float* bo   = (const float*)d_in[5];
  float* out = (float*)d_out;
  char* ws = (char*)d_ws;

  u16* hsb   = (u16*)(ws);                 // 8 MB [4096][1024]  (reused as AOb after QKV gemm)
  u16* Wqkvt = (u16*)(ws + (8  << 20));    // 6 MB [3072][1024]
  u16* Wot   = (u16*)(ws + (14 << 20));    // 2 MB [1024][1024]
  u16* Qb    = (u16*)(ws + (16 << 20));    // 8 MB [2,16,2048,64]
  u16* Kb    = (u16*)(ws + (24 << 20));    // 8 MB
  u16* Vb    = (u16*)(ws + (32 << 20));    // 8 MB
  u16* Vtb   = (u16*)(ws + (40 << 20));    // 8 MB [2,16,64,2048]
  u16* AOb   = (u16*)(ws + (48 << 20));    // 8 MB [4096][1024]

  k_convert<<<2048, 256, 0, stream>>>(hs, hsb, 4096 * 1024);
  k_tconv<<<dim3(3072 / 64, 1024 / 64), 256, 0, stream>>>(Wqkv, Wqkvt, 1024, 3072);
  k_tconv<<<dim3(1024 / 64, 1024 / 64), 256, 0, stream>>>(Wo, Wot, 1024, 1024);
  k_gemm128<0><<<dim3(24, 32), 256, 0, stream>>>(hsb, Wqkvt, 4096, 3072, 1024, bqkv,
                                                 Qb, Kb, Vb, nullptr);
  k_vtrans<<<1024, 256, 0, stream>>>(Vb, Vtb);
  k_attn<<<1024, 256, 0, stream>>>(Qb, Kb, Vtb, mask, AOb);
  k_gemm128<1><<<dim3(8, 32), 256, 0, stream>>>(AOb, Wot, 4096, 1024, 1024, bo,
                                                nullptr, nullptr, nullptr, out);
}